// Round 3
// baseline (43.960 us; speedup 1.0000x reference)
//
#include <hip/hip_runtime.h>
#include <hip/hip_bf16.h>

// Problem constants (from reference setup_inputs):
//   B=64, S=512, DB=768, DW=100, W=512
//   bert_x:   [B, S, DB]   float32
//   w2v:      [B, W, DW]   float32
//   mappings: [B, S-1]     int32
//   out:      [B, S, DB+DW]=[64,512,868] float32
// Semantics: row 0 of each batch is zero. Row r (1..S-1) is
//   [bert_x[b,r,:], w2v[b, mappings[b,r-1], :]] if all mappings[b,0..r-1] != -1
//   else zeros.
//
// R2: explicit load-batching (8 float4 in flight per thread — VGPR=8 in R1
// showed the compiler serialized load->store with no MLP) + nontemporal
// stores for the write-once output stream.

#define B_    64
#define S_    512
#define SM1_  511
#define DB_   768
#define DW_   100
#define DOUT_ 868            // DB+DW
#define DOUT4_ 217           // DOUT/4
#define DB4_  192            // DB/4
#define W_    512
#define ROWS_PER_BLK_ 8      // S_/ROWS_PER_BLK_ chunks per batch

typedef float fvec4 __attribute__((ext_vector_type(4)));

__global__ __launch_bounds__(256) void fused_fuse_rows_kernel(
        const float* __restrict__ bert_x,
        const float* __restrict__ w2v,
        const int* __restrict__ mappings,
        float* __restrict__ out) {
    const int blk   = blockIdx.x;        // b * (S/ROWS_PER_BLK) + chunk
    const int b     = blk >> 6;          // 64 chunks per batch
    const int chunk = blk & 63;
    const int r0    = chunk * ROWS_PER_BLK_;
    const int tid   = threadIdx.x;       // 0..255

    // --- redundant per-block first-invalid scan (batch-local, 2 KB, L2-hot) ---
    __shared__ int s_min;
    if (tid == 0) s_min = SM1_;
    __syncthreads();
    const int* __restrict__ mrow = mappings + b * SM1_;
    #pragma unroll
    for (int i = tid; i < SM1_; i += 256) {
        if (mrow[i] == -1) atomicMin(&s_min, i);
    }
    __syncthreads();
    const int fi = s_min;                // rows 1..fi are valid (r-1 < fi)

    const fvec4* __restrict__ bbase = reinterpret_cast<const fvec4*>(
        bert_x + (size_t)b * S_ * DB_);
    const fvec4* __restrict__ wbase = reinterpret_cast<const fvec4*>(
        w2v + (size_t)b * W_ * DW_);
    fvec4* __restrict__ obase = reinterpret_cast<fvec4*>(
        out + (size_t)b * S_ * DOUT_);

    // --- phase 1: issue all 8 row-loads (independent, 8 loads in flight) ---
    fvec4 vals[ROWS_PER_BLK_];
    #pragma unroll
    for (int rr = 0; rr < ROWS_PER_BLK_; ++rr) {
        const int r = r0 + rr;
        const bool valid = (r != 0) && ((r - 1) < fi);
        fvec4 v = (fvec4)(0.f);
        if (valid) {
            if (tid < DB4_) {
                v = __builtin_nontemporal_load(&bbase[(size_t)r * DB4_ + tid]);
            } else if (tid < DOUT4_) {
                int w = mrow[r - 1];
                if (w < 0) w = 0;        // reference clip (unreachable for valid rows)
                v = wbase[(size_t)w * (DW_ / 4) + (tid - DB4_)];
            }
        }
        vals[rr] = v;
    }

    // --- phase 2: store all 8 rows (nontemporal: write-once stream) ---
    if (tid < DOUT4_) {
        #pragma unroll
        for (int rr = 0; rr < ROWS_PER_BLK_; ++rr) {
            const int r = r0 + rr;
            __builtin_nontemporal_store(vals[rr], &obase[(size_t)r * DOUT4_ + tid]);
        }
    }
}

extern "C" void kernel_launch(void* const* d_in, const int* in_sizes, int n_in,
                              void* d_out, int out_size, void* d_ws, size_t ws_size,
                              hipStream_t stream) {
    const float* bert_x = (const float*)d_in[0];
    const float* w2v    = (const float*)d_in[1];
    const int* mappings = (const int*)d_in[2];
    float* out = (float*)d_out;

    fused_fuse_rows_kernel<<<B_ * (S_ / ROWS_PER_BLK_), 256, 0, stream>>>(
        bert_x, w2v, mappings, out);
}

// Round 4
// 40.011 us; speedup vs baseline: 1.0987x; 1.0987x over previous
//
#include <hip/hip_runtime.h>
#include <hip/hip_bf16.h>

// Problem constants (from reference setup_inputs):
//   B=64, S=512, DB=768, DW=100, W=512
//   bert_x:   [B, S, DB]   float32
//   w2v:      [B, W, DW]   float32
//   mappings: [B, S-1]     int32
//   out:      [B, S, DB+DW]=[64,512,868] float32
// Semantics: row 0 of each batch is zero. Row r (1..S-1) is
//   [bert_x[b,r,:], w2v[b, mappings[b,r-1], :]] if all mappings[b,0..r-1] != -1
//   else zeros.
//
// R3: flat per-batch output indexing — 100% lane utilization (R1/R2 wasted
// 39/256 lanes), 14 float4s per thread loaded into registers before storing
// (MLP), dense nontemporal stores (write-once stream, keep L3 for inputs),
// REGULAR loads (R2's NT loads defeated cross-replay L3 residency of bert_x).

#define B_    64
#define S_    512
#define SM1_  511
#define DB_   768
#define DW_   100
#define DOUT_ 868            // DB+DW
#define DOUT4_ 217           // DOUT/4
#define DB4_  192            // DB/4
#define DW4_  25             // DW/4
#define W_    512
#define BLKS_PER_BATCH_ 31
#define K_    14             // float4s per thread; 31*256*14 = 512*217 exactly

typedef float fvec4 __attribute__((ext_vector_type(4)));

__global__ __launch_bounds__(256) void fused_flat_kernel(
        const float* __restrict__ bert_x,
        const float* __restrict__ w2v,
        const int* __restrict__ mappings,
        float* __restrict__ out) {
    const int blk   = blockIdx.x;
    const int b     = blk / BLKS_PER_BATCH_;
    const int chunk = blk - b * BLKS_PER_BATCH_;
    const int tid   = threadIdx.x;

    // --- per-block first-invalid scan (batch-local 2 KB, L2-hot) ---
    __shared__ int s_min;
    if (tid == 0) s_min = SM1_;
    __syncthreads();
    const int* __restrict__ mrow = mappings + b * SM1_;
    for (int i = tid; i < SM1_; i += 256) {
        if (mrow[i] == -1) atomicMin(&s_min, i);
    }
    __syncthreads();
    const int fi = s_min;                // rows 1..fi are valid (r-1 < fi)

    const fvec4* __restrict__ bbase = reinterpret_cast<const fvec4*>(
        bert_x + (size_t)b * S_ * DB_);
    const fvec4* __restrict__ wbase = reinterpret_cast<const fvec4*>(
        w2v + (size_t)b * W_ * DW_);
    fvec4* __restrict__ obase = reinterpret_cast<fvec4*>(
        out + (size_t)b * S_ * DOUT_);

    const int idx0 = chunk * (256 * K_) + tid;   // within-batch float4 index

    // --- phase 1: gather K_ elements into registers (independent loads) ---
    fvec4 v[K_];
    #pragma unroll
    for (int k = 0; k < K_; ++k) {
        const int idx = idx0 + k * 256;          // < 111104 < 2^17
        const int row = idx / DOUT4_;            // compiler magic-div by 217
        const int c4  = idx - row * DOUT4_;
        fvec4 val = (fvec4)(0.f);
        const bool valid = (row != 0) && ((row - 1) < fi);
        if (valid) {
            if (c4 < DB4_) {
                val = bbase[(size_t)row * DB4_ + c4];
            } else {
                int w = mrow[row - 1];
                if (w < 0) w = 0;                // reference clip (unreachable when valid)
                val = wbase[(size_t)w * DW4_ + (c4 - DB4_)];
            }
        }
        v[k] = val;
    }

    // --- phase 2: dense nontemporal stores (write-once output stream) ---
    #pragma unroll
    for (int k = 0; k < K_; ++k) {
        __builtin_nontemporal_store(v[k], &obase[idx0 + k * 256]);
    }
}

extern "C" void kernel_launch(void* const* d_in, const int* in_sizes, int n_in,
                              void* d_out, int out_size, void* d_ws, size_t ws_size,
                              hipStream_t stream) {
    const float* bert_x = (const float*)d_in[0];
    const float* w2v    = (const float*)d_in[1];
    const int* mappings = (const int*)d_in[2];
    float* out = (float*)d_out;

    fused_flat_kernel<<<B_ * BLKS_PER_BATCH_, 256, 0, stream>>>(
        bert_x, w2v, mappings, out);
}

// Round 5
// 39.539 us; speedup vs baseline: 1.1118x; 1.0119x over previous
//
#include <hip/hip_runtime.h>
#include <hip/hip_bf16.h>

// Problem constants (from reference setup_inputs):
//   B=64, S=512, DB=768, DW=100, W=512
//   bert_x:   [B, S, DB]   float32
//   w2v:      [B, W, DW]   float32
//   mappings: [B, S-1]     int32
//   out:      [B, S, DB+DW]=[64,512,868] float32
// Semantics: row 0 of each batch is zero. Row r (1..S-1) is
//   [bert_x[b,r,:], w2v[b, mappings[b,r-1], :]] if all mappings[b,0..r-1] != -1
//   else zeros.
//
// R4: dependency restructure. Main loads are issued speculatively at t=0
// (addresses never depend on validity); the first-invalid index is computed
// per-wave (8 ints/lane + __shfl_xor min-reduce — no LDS, no barrier) UNDER
// the main loads' latency; validity is applied as a select at store time.
// K=7 float4/thread keeps VGPR <= 64 so 8 waves/SIMD survive.

#define B_    64
#define S_    512
#define SM1_  511
#define DB_   768
#define DW_   100
#define DOUT_ 868            // DB+DW
#define DOUT4_ 217           // DOUT/4
#define DB4_  192            // DB/4
#define DW4_  25             // DW/4
#define W_    512
#define K_    7              // float4s per thread
#define BLKS_PER_BATCH_ 62   // 62*256*7 = 111104 = 512*217 exactly

typedef float fvec4 __attribute__((ext_vector_type(4)));

__global__ __launch_bounds__(256, 8) void fused_spec_kernel(
        const float* __restrict__ bert_x,
        const float* __restrict__ w2v,
        const int* __restrict__ mappings,
        float* __restrict__ out) {
    const int blk   = blockIdx.x;
    const int b     = blk / BLKS_PER_BATCH_;
    const int chunk = blk - b * BLKS_PER_BATCH_;
    const int tid   = threadIdx.x;
    const int lane  = tid & 63;

    const int* __restrict__ mrow = mappings + b * SM1_;

    // --- issue scan loads (8 ints/lane, coalesced, L2-hot) ---
    int sm[8];
    #pragma unroll
    for (int j = 0; j < 8; ++j) {
        const int i = lane + j * 64;
        sm[j] = (i < SM1_) ? mrow[i] : 0;
    }

    const fvec4* __restrict__ bbase = reinterpret_cast<const fvec4*>(
        bert_x + (size_t)b * S_ * DB_);
    const fvec4* __restrict__ wbase = reinterpret_cast<const fvec4*>(
        w2v + (size_t)b * W_ * DW_);
    fvec4* __restrict__ obase = reinterpret_cast<fvec4*>(
        out + (size_t)b * S_ * DOUT_);

    const int idx0 = chunk * (256 * K_) + tid;   // within-batch float4 index

    // --- issue all K_ main loads speculatively (validity applied later) ---
    fvec4 v[K_];
    #pragma unroll
    for (int k = 0; k < K_; ++k) {
        const int idx = idx0 + k * 256;          // < 111104 < 2^17
        const int row = idx / DOUT4_;
        const int c4  = idx - row * DOUT4_;
        if (c4 < DB4_) {
            v[k] = bbase[(size_t)row * DB4_ + c4];
        } else {
            const int wr = (row > 0) ? (row - 1) : 0;  // safe addr for row 0
            int w = mrow[wr];
            if (w < 0) w = 0;                          // reference clip
            v[k] = wbase[(size_t)w * DW4_ + (c4 - DB4_)];
        }
    }

    // --- wave-local first-invalid reduce (runs under main-load latency) ---
    int m = SM1_;
    #pragma unroll
    for (int j = 0; j < 8; ++j) {
        const int i = lane + j * 64;
        if (sm[j] == -1 && i < m) m = i;
    }
    #pragma unroll
    for (int off = 32; off > 0; off >>= 1) {
        const int o = __shfl_xor(m, off, 64);
        if (o < m) m = o;
    }
    // rows 1..m are valid (row-1 < m)

    // --- mask + dense nontemporal stores ---
    #pragma unroll
    for (int k = 0; k < K_; ++k) {
        const int idx = idx0 + k * 256;
        const int row = idx / DOUT4_;
        const bool valid = (row != 0) && ((row - 1) < m);
        fvec4 o = valid ? v[k] : (fvec4)(0.f);
        __builtin_nontemporal_store(o, &obase[idx]);
    }
}

extern "C" void kernel_launch(void* const* d_in, const int* in_sizes, int n_in,
                              void* d_out, int out_size, void* d_ws, size_t ws_size,
                              hipStream_t stream) {
    const float* bert_x = (const float*)d_in[0];
    const float* w2v    = (const float*)d_in[1];
    const int* mappings = (const int*)d_in[2];
    float* out = (float*)d_out;

    fused_spec_kernel<<<B_ * BLKS_PER_BATCH_, 256, 0, stream>>>(
        bert_x, w2v, mappings, out);
}

// Round 6
// 39.235 us; speedup vs baseline: 1.1204x; 1.0078x over previous
//
#include <hip/hip_runtime.h>
#include <hip/hip_bf16.h>

// Problem constants (from reference setup_inputs):
//   B=64, S=512, DB=768, DW=100, W=512
//   bert_x:   [B, S, DB]   float32
//   w2v:      [B, W, DW]   float32
//   mappings: [B, S-1]     int32
//   out:      [B, S, DB+DW]=[64,512,868] float32
// Semantics: row 0 of each batch is zero. Row r (1..S-1) is
//   [bert_x[b,r,:], w2v[b, mappings[b,r-1], :]] if all mappings[b,0..r-1] != -1
//   else zeros.
//
// R5: one-round persistent grid — 1984 blocks (7.75/CU, all co-resident at
// VGPR<=64) each owning a same-batch chunk PAIR (62 chunks/batch, even, so
// pairs never straddle batches): one wave-local scan, two K=7 speculative
// load/store groups. sched_barrier(0) pins each 7-load group fully in
// flight before dependent code (R3/R4: compiler collapsed the window).

#define B_    64
#define S_    512
#define SM1_  511
#define DB_   768
#define DW_   100
#define DOUT_ 868            // DB+DW
#define DOUT4_ 217           // DOUT/4
#define DB4_  192            // DB/4
#define DW4_  25             // DW/4
#define W_    512
#define K_    7              // float4s per thread per chunk
#define CHUNK4_ (256 * K_)   // 1792 float4s per chunk
#define CHUNKS_PER_BATCH_ 62 // 62*1792 = 111104 = 512*217 exactly
#define NBLK_ (B_ * CHUNKS_PER_BATCH_ / 2)   // 1984

typedef float fvec4 __attribute__((ext_vector_type(4)));

__global__ __launch_bounds__(256, 8) void fused_persist_kernel(
        const float* __restrict__ bert_x,
        const float* __restrict__ w2v,
        const int* __restrict__ mappings,
        float* __restrict__ out) {
    const int blk  = blockIdx.x;         // 0..1983
    const int g0   = blk * 2;            // global chunk index (pair start)
    const int b    = g0 / CHUNKS_PER_BATCH_;
    const int c0   = g0 - b * CHUNKS_PER_BATCH_;   // even; c1 = c0+1 same batch
    const int tid  = threadIdx.x;
    const int lane = tid & 63;

    const int* __restrict__ mrow = mappings + b * SM1_;
    const fvec4* __restrict__ bbase = reinterpret_cast<const fvec4*>(
        bert_x + (size_t)b * S_ * DB_);
    const fvec4* __restrict__ wbase = reinterpret_cast<const fvec4*>(
        w2v + (size_t)b * W_ * DW_);
    fvec4* __restrict__ obase = reinterpret_cast<fvec4*>(
        out + (size_t)b * S_ * DOUT_);

    const int idxA = c0 * CHUNK4_ + tid;           // chunk 0 base float4 idx
    const int idxB = idxA + CHUNK4_;               // chunk 1

    // --- chunk A: issue all 7 loads speculatively ---
    fvec4 vA[K_];
    #pragma unroll
    for (int k = 0; k < K_; ++k) {
        const int idx = idxA + k * 256;
        const int row = idx / DOUT4_;
        const int c4  = idx - row * DOUT4_;
        if (c4 < DB4_) {
            vA[k] = bbase[(size_t)row * DB4_ + c4];
        } else {
            const int wr = (row > 0) ? (row - 1) : 0;
            int w = mrow[wr];
            if (w < 0) w = 0;                      // reference clip
            vA[k] = wbase[(size_t)w * DW4_ + (c4 - DB4_)];
        }
    }
    __builtin_amdgcn_sched_barrier(0);   // keep all 7 loads issued up-front

    // --- scan loads + wave-local first-invalid reduce (under load latency) ---
    int m = SM1_;
    #pragma unroll
    for (int j = 0; j < 8; ++j) {
        const int i = lane + j * 64;
        if (i < SM1_ && mrow[i] == -1 && i < m) m = i;
    }
    #pragma unroll
    for (int off = 32; off > 0; off >>= 1) {
        const int o = __shfl_xor(m, off, 64);
        if (o < m) m = o;
    }
    // rows 1..m are valid (row-1 < m)

    // --- chunk A: mask + dense NT stores ---
    #pragma unroll
    for (int k = 0; k < K_; ++k) {
        const int idx = idxA + k * 256;
        const int row = idx / DOUT4_;
        const bool valid = (row != 0) && ((row - 1) < m);
        __builtin_nontemporal_store(valid ? vA[k] : (fvec4)(0.f), &obase[idx]);
    }

    // --- chunk B: issue all 7 loads ---
    fvec4 vB[K_];
    #pragma unroll
    for (int k = 0; k < K_; ++k) {
        const int idx = idxB + k * 256;
        const int row = idx / DOUT4_;
        const int c4  = idx - row * DOUT4_;
        if (c4 < DB4_) {
            vB[k] = bbase[(size_t)row * DB4_ + c4];
        } else {
            const int wr = (row > 0) ? (row - 1) : 0;
            int w = mrow[wr];
            if (w < 0) w = 0;
            vB[k] = wbase[(size_t)w * DW4_ + (c4 - DB4_)];
        }
    }
    __builtin_amdgcn_sched_barrier(0);

    // --- chunk B: mask + dense NT stores ---
    #pragma unroll
    for (int k = 0; k < K_; ++k) {
        const int idx = idxB + k * 256;
        const int row = idx / DOUT4_;
        const bool valid = (row != 0) && ((row - 1) < m);
        __builtin_nontemporal_store(valid ? vB[k] : (fvec4)(0.f), &obase[idx]);
    }
}

extern "C" void kernel_launch(void* const* d_in, const int* in_sizes, int n_in,
                              void* d_out, int out_size, void* d_ws, size_t ws_size,
                              hipStream_t stream) {
    const float* bert_x = (const float*)d_in[0];
    const float* w2v    = (const float*)d_in[1];
    const int* mappings = (const int*)d_in[2];
    float* out = (float*)d_out;

    fused_persist_kernel<<<NBLK_, 256, 0, stream>>>(bert_x, w2v, mappings, out);
}